// Round 1
// baseline (335.840 us; speedup 1.0000x reference)
//
#include <hip/hip_runtime.h>
#include <math.h>

#define IMG_H 2048
#define IMG_W 2048
#define TX 64
#define TY 32
#define HALO 3
#define IN_W (TX + 2 * HALO)  // 70
#define IN_H (TY + 2 * HALO)  // 38

// Order-preserving float->uint key: ascending float order == ascending uint order.
__device__ __forceinline__ unsigned f2key(unsigned u) {
    unsigned mask = (unsigned)(((int)u >> 31)) | 0x80000000u;
    return u ^ mask;
}

// ---------------- Pass 1: 2048-bin histogram of top 11 key bits ----------------
__global__ __launch_bounds__(256) void hist_kernel(const float4* __restrict__ x, int n4,
                                                   unsigned* __restrict__ ghist) {
    __shared__ unsigned h[4 * 2048];  // per-wave private copies (cuts LDS atomic contention 4x)
    const int wave = threadIdx.x >> 6;
    unsigned* hw = &h[wave * 2048];
    for (int i = threadIdx.x; i < 4 * 2048; i += 256) h[i] = 0;
    __syncthreads();
    const int stride = gridDim.x * blockDim.x;
    for (int i = blockIdx.x * blockDim.x + threadIdx.x; i < n4; i += stride) {
        float4 v = x[i];
        atomicAdd(&hw[f2key(__float_as_uint(v.x)) >> 21], 1u);
        atomicAdd(&hw[f2key(__float_as_uint(v.y)) >> 21], 1u);
        atomicAdd(&hw[f2key(__float_as_uint(v.z)) >> 21], 1u);
        atomicAdd(&hw[f2key(__float_as_uint(v.w)) >> 21], 1u);
    }
    __syncthreads();
    for (int b = threadIdx.x; b < 2048; b += 256) {
        unsigned s = h[b] + h[2048 + b] + h[4096 + b] + h[6144 + b];
        if (s) atomicAdd(&ghist[b], s);
    }
}

// ---------------- Find bucket containing rank k, and residual rank ----------------
__global__ __launch_bounds__(256) void find_bucket_kernel(const unsigned* __restrict__ ghist,
                                                          unsigned k, unsigned* __restrict__ ctrl) {
    __shared__ unsigned lh[2048];
    __shared__ unsigned part[256];
    for (int i = threadIdx.x; i < 2048; i += 256) lh[i] = ghist[i];
    __syncthreads();
    unsigned s = 0;
    for (int j = 0; j < 8; ++j) s += lh[threadIdx.x * 8 + j];
    part[threadIdx.x] = s;
    __syncthreads();
    if (threadIdx.x == 0) {
        unsigned cum = 0;
        int t = 0;
        while (t < 255 && cum + part[t] <= k) { cum += part[t]; ++t; }
        int b = t * 8;
        while (b < 2047 && cum + lh[b] <= k) { cum += lh[b]; ++b; }
        ctrl[0] = (unsigned)b;   // bucket (top 11 key bits)
        ctrl[1] = k - cum;       // residual 0-indexed rank within bucket
    }
}

// ---------------- Pass 2: compact keys of the selected bucket ----------------
__global__ __launch_bounds__(256) void compact_kernel(const float4* __restrict__ x, int n4,
                                                      const unsigned* __restrict__ ctrl,
                                                      unsigned* __restrict__ counter,
                                                      unsigned* __restrict__ cand, unsigned cap) {
    const unsigned bucket = ctrl[0];
    const int stride = gridDim.x * blockDim.x;
    for (int i = blockIdx.x * blockDim.x + threadIdx.x; i < n4; i += stride) {
        float4 v = x[i];
        unsigned ks0 = f2key(__float_as_uint(v.x));
        unsigned ks1 = f2key(__float_as_uint(v.y));
        unsigned ks2 = f2key(__float_as_uint(v.z));
        unsigned ks3 = f2key(__float_as_uint(v.w));
        if ((ks0 >> 21) == bucket) { unsigned p = atomicAdd(counter, 1u); if (p < cap) cand[p] = ks0; }
        if ((ks1 >> 21) == bucket) { unsigned p = atomicAdd(counter, 1u); if (p < cap) cand[p] = ks1; }
        if ((ks2 >> 21) == bucket) { unsigned p = atomicAdd(counter, 1u); if (p < cap) cand[p] = ks2; }
        if ((ks3 >> 21) == bucket) { unsigned p = atomicAdd(counter, 1u); if (p < cap) cand[p] = ks3; }
    }
}

// ---------------- Select exact median among candidates (single block) ----------------
__global__ __launch_bounds__(256) void select_kernel(const unsigned* __restrict__ ctrl,
                                                     const unsigned* __restrict__ counter,
                                                     const unsigned* __restrict__ cand, unsigned cap,
                                                     float* __restrict__ medp) {
    __shared__ unsigned h2[2048];
    __shared__ unsigned part[256];
    __shared__ unsigned sres[2];
    const unsigned Mc = *counter;
    const unsigned M = Mc < cap ? Mc : cap;
    const unsigned r = ctrl[1];
    const unsigned bucket = ctrl[0];

    // Level 2: key bits [20:10] (2048 bins)
    for (int i = threadIdx.x; i < 2048; i += 256) h2[i] = 0;
    __syncthreads();
    for (unsigned i = threadIdx.x; i < M; i += 256) atomicAdd(&h2[(cand[i] >> 10) & 0x7FFu], 1u);
    __syncthreads();
    unsigned s = 0;
    for (int j = 0; j < 8; ++j) s += h2[threadIdx.x * 8 + j];
    part[threadIdx.x] = s;
    __syncthreads();
    if (threadIdx.x == 0) {
        unsigned cum = 0;
        int t = 0;
        while (t < 255 && cum + part[t] <= r) { cum += part[t]; ++t; }
        int b = t * 8;
        while (b < 2047 && cum + h2[b] <= r) { cum += h2[b]; ++b; }
        sres[0] = (unsigned)b;
        sres[1] = r - cum;
    }
    __syncthreads();
    const unsigned b2 = sres[0], r2 = sres[1];
    const unsigned pref = (bucket << 11) | b2;  // top 22 key bits

    // Level 3: key bits [9:0] (1024 bins) — reuse h2[0..1023]
    for (int i = threadIdx.x; i < 1024; i += 256) h2[i] = 0;
    __syncthreads();
    for (unsigned i = threadIdx.x; i < M; i += 256) {
        unsigned key = cand[i];
        if ((key >> 10) == pref) atomicAdd(&h2[key & 0x3FFu], 1u);
    }
    __syncthreads();
    s = 0;
    for (int j = 0; j < 4; ++j) s += h2[threadIdx.x * 4 + j];
    part[threadIdx.x] = s;
    __syncthreads();
    if (threadIdx.x == 0) {
        unsigned cum = 0;
        int t = 0;
        while (t < 255 && cum + part[t] <= r2) { cum += part[t]; ++t; }
        int b = t * 4;
        while (b < 1023 && cum + h2[b] <= r2) { cum += h2[b]; ++b; }
        unsigned key = (pref << 10) | (unsigned)b;
        unsigned u = (key & 0x80000000u) ? (key ^ 0x80000000u) : ~key;
        *medp = __uint_as_float(u);
    }
}

// ---------------- Fused threshold + 7x7 maxpool + NMS ----------------
__global__ __launch_bounds__(256) void nms_kernel(const float* __restrict__ x,
                                                  float* __restrict__ out,
                                                  const float* __restrict__ medp) {
    __shared__ float sin_[IN_H * IN_W];
    __shared__ float shm[IN_H * TX];
    const float med = *medp;
    const int tx0 = blockIdx.x * TX;
    const int ty0 = blockIdx.y * TY;
    const size_t ib = (size_t)blockIdx.z * (size_t)(IMG_H * IMG_W);
    const float* img = x + ib;
    float* oimg = out + ib;

    // Load halo tile, thresholding on the fly; out-of-image -> -inf (pool padding)
    for (int i = threadIdx.x; i < IN_H * IN_W; i += 256) {
        int rr = i / IN_W;
        int cc = i - rr * IN_W;
        int gy = ty0 + rr - HALO;
        int gx = tx0 + cc - HALO;
        float v = -INFINITY;
        if ((unsigned)gy < (unsigned)IMG_H && (unsigned)gx < (unsigned)IMG_W) {
            float xv = img[(size_t)gy * IMG_W + gx];
            v = (xv > med) ? xv : 0.0f;
        }
        sin_[i] = v;
    }
    __syncthreads();

    // Horizontal 7-tap max (separable pooling), for all IN_H rows x TX cols
    for (int i = threadIdx.x; i < IN_H * TX; i += 256) {
        int rr = i >> 6;
        int cc = i & 63;
        const float* p = &sin_[rr * IN_W + cc];
        float m = p[0];
        m = fmaxf(m, p[1]); m = fmaxf(m, p[2]); m = fmaxf(m, p[3]);
        m = fmaxf(m, p[4]); m = fmaxf(m, p[5]); m = fmaxf(m, p[6]);
        shm[i] = m;
    }
    __syncthreads();

    // Vertical 7-tap max + NMS compare + store
    for (int i = threadIdx.x; i < TY * TX; i += 256) {
        int rr = i >> 6;
        int cc = i & 63;
        const float* q = &shm[rr * TX + cc];
        float m = q[0];
        m = fmaxf(m, q[64]);  m = fmaxf(m, q[128]); m = fmaxf(m, q[192]);
        m = fmaxf(m, q[256]); m = fmaxf(m, q[320]); m = fmaxf(m, q[384]);
        float t = sin_[(rr + HALO) * IN_W + (cc + HALO)];
        oimg[(size_t)(ty0 + rr) * IMG_W + (tx0 + cc)] = (t == m) ? t : 0.0f;
    }
}

extern "C" void kernel_launch(void* const* d_in, const int* in_sizes, int n_in,
                              void* d_out, int out_size, void* d_ws, size_t ws_size,
                              hipStream_t stream) {
    const float* x = (const float*)d_in[0];
    float* out = (float*)d_out;
    const int n = in_sizes[0];          // 8*2048*2048 = 33,554,432
    const int n4 = n / 4;
    const unsigned k = (unsigned)((n - 1) / 2);  // lower-median rank (0-indexed)

    unsigned char* ws = (unsigned char*)d_ws;
    unsigned* ghist = (unsigned*)ws;                 // 2048 u32
    unsigned* ctrl = (unsigned*)(ws + 2048 * 4);     // [0]=bucket [1]=rank [2]=counter [3]=med bits
    unsigned* counter = ctrl + 2;
    float* medp = (float*)(ctrl + 3);
    unsigned* cand = ctrl + 4;
    const size_t reserved = 2048 * 4 + 16;
    unsigned cap = 0;
    if (ws_size > reserved + 4) {
        size_t c = (ws_size - reserved) / 4;
        cap = (unsigned)(c > (size_t)(1u << 20) ? (size_t)(1u << 20) : c);
    }

    // ws is re-poisoned to 0xAA before every timed launch: zero hist + control words.
    hipMemsetAsync(d_ws, 0, reserved, stream);

    hist_kernel<<<1024, 256, 0, stream>>>((const float4*)x, n4, ghist);
    find_bucket_kernel<<<1, 256, 0, stream>>>(ghist, k, ctrl);
    compact_kernel<<<1024, 256, 0, stream>>>((const float4*)x, n4, ctrl, counter, cand, cap);
    select_kernel<<<1, 256, 0, stream>>>(ctrl, counter, cand, cap, medp);

    const int batch = n / (IMG_H * IMG_W);
    dim3 grid(IMG_W / TX, IMG_H / TY, batch);
    nms_kernel<<<grid, 256, 0, stream>>>(x, out, medp);
}